// Round 1
// baseline (937.237 us; speedup 1.0000x reference)
//
#include <hip/hip_runtime.h>
#include <math.h>

#define H_HEADS 8
#define C_DIM   32
#define HC      256
#define F_IN    512
#define NEG_SLOPE 0.2f

// ---------------------------------------------------------------------------
// Tiled fp32 GEMM: C[M,Ncols] = A[M,K] * B[K,Ncols].  64x64 tile, 4x4 micro.
// ---------------------------------------------------------------------------
__global__ __launch_bounds__(256) void gemm_tile(const float* __restrict__ A,
    const float* __restrict__ B, float* __restrict__ C, int M, int K, int Ncols)
{
    __shared__ float As[16][64];   // transposed: As[k][m]
    __shared__ float Bs[16][64];   // Bs[k][n]
    const int tid = threadIdx.x;
    const int bm = blockIdx.x * 64;
    const int bn = blockIdx.y * 64;
    const int tx = tid & 15, ty = tid >> 4;
    const int arow = tid >> 2, aq = tid & 3;
    const int brow = tid >> 4, bq = tid & 15;
    float acc[4][4] = {};
    const int grA = bm + arow;
    for (int k0 = 0; k0 < K; k0 += 16) {
        float4 av = make_float4(0.f, 0.f, 0.f, 0.f);
        if (grA < M) av = *(const float4*)(A + (size_t)grA * K + k0 + aq * 4);
        As[aq * 4 + 0][arow] = av.x;
        As[aq * 4 + 1][arow] = av.y;
        As[aq * 4 + 2][arow] = av.z;
        As[aq * 4 + 3][arow] = av.w;
        *(float4*)&Bs[brow][bq * 4] =
            *(const float4*)(B + (size_t)(k0 + brow) * Ncols + bn + bq * 4);
        __syncthreads();
        #pragma unroll
        for (int k = 0; k < 16; ++k) {
            float4 a4 = *(const float4*)&As[k][ty * 4];
            float4 b4 = *(const float4*)&Bs[k][tx * 4];
            float a[4] = {a4.x, a4.y, a4.z, a4.w};
            float b[4] = {b4.x, b4.y, b4.z, b4.w};
            #pragma unroll
            for (int i = 0; i < 4; ++i)
                #pragma unroll
                for (int j = 0; j < 4; ++j)
                    acc[i][j] = fmaf(a[i], b[j], acc[i][j]);
        }
        __syncthreads();
    }
    #pragma unroll
    for (int i = 0; i < 4; ++i) {
        int gr = bm + ty * 4 + i;
        if (gr < M) {
            float4 o = make_float4(acc[i][0], acc[i][1], acc[i][2], acc[i][3]);
            *(float4*)(C + (size_t)gr * Ncols + bn + tx * 4) = o;
        }
    }
}

// ---------------------------------------------------------------------------
// alpha_s[n,h] = sum_c h[n,h,c]*a_s[h,c]; same for alpha_d. One block per node.
// ---------------------------------------------------------------------------
__global__ __launch_bounds__(256) void alphas_kernel(const float* __restrict__ h,
    const float* __restrict__ a_s, const float* __restrict__ a_d,
    float* __restrict__ alpha_s, float* __restrict__ alpha_d)
{
    const int n = blockIdx.x;
    const int t = threadIdx.x;                 // t = head*32 + c
    float v = h[(size_t)n * HC + t];
    float ps = v * a_s[t];
    float pd = v * a_d[t];
    #pragma unroll
    for (int off = 16; off > 0; off >>= 1) {
        ps += __shfl_xor(ps, off);
        pd += __shfl_xor(pd, off);
    }
    if ((t & 31) == 0) {
        int hh = t >> 5;
        alpha_s[(size_t)n * H_HEADS + hh] = ps;
        alpha_d[(size_t)n * H_HEADS + hh] = pd;
    }
}

// ---------------------------------------------------------------------------
// CSR build: zero, histogram (incl. self-loops), 2-level exclusive scan, scatter
// ---------------------------------------------------------------------------
__global__ void zero_int(int* __restrict__ p, int n)
{
    int i = blockIdx.x * 256 + threadIdx.x;
    if (i < n) p[i] = 0;
}

__global__ void hist_kernel(const int* __restrict__ ei, int E, int N,
                            int* __restrict__ cnt)
{
    int e = blockIdx.x * 256 + threadIdx.x;
    if (e < E) atomicAdd(&cnt[ei[E + e]], 1);          // dst row of edge_index
    else if (e < E + N) atomicAdd(&cnt[e - E], 1);     // self loop
}

__global__ __launch_bounds__(256) void scan_sum(const int* __restrict__ cnt, int n,
                                                int* __restrict__ chunk_sum)
{
    __shared__ int lds[256];
    int b = blockIdx.x, t = threadIdx.x;
    int base = b * 1024 + t * 4;
    int s = 0;
    #pragma unroll
    for (int j = 0; j < 4; ++j) { int i = base + j; if (i < n) s += cnt[i]; }
    lds[t] = s; __syncthreads();
    for (int off = 128; off > 0; off >>= 1) {
        if (t < off) lds[t] += lds[t + off];
        __syncthreads();
    }
    if (t == 0) chunk_sum[b] = lds[0];
}

__global__ void scan_top(const int* __restrict__ chunk_sum, int nch,
                         int* __restrict__ chunk_off, int* __restrict__ row_ptr,
                         int n_nodes)
{
    int t = threadIdx.x;   // 64 threads
    int v = (t < nch) ? chunk_sum[t] : 0;
    int inc = v;
    #pragma unroll
    for (int off = 1; off < 64; off <<= 1) {
        int u = __shfl_up(inc, off);
        if (t >= off) inc += u;
    }
    if (t < nch) chunk_off[t] = inc - v;
    if (t == 63) row_ptr[n_nodes] = inc;   // total = E + N
}

__global__ __launch_bounds__(256) void scan_local(const int* __restrict__ cnt, int n,
    const int* __restrict__ chunk_off, int* __restrict__ row_ptr)
{
    __shared__ int lds[256];
    int b = blockIdx.x, t = threadIdx.x;
    int base = b * 1024 + t * 4;
    int v[4]; int s = 0;
    #pragma unroll
    for (int j = 0; j < 4; ++j) { int i = base + j; v[j] = (i < n) ? cnt[i] : 0; s += v[j]; }
    lds[t] = s; __syncthreads();
    for (int off = 1; off < 256; off <<= 1) {
        int u = (t >= off) ? lds[t - off] : 0;
        __syncthreads();
        lds[t] += u;
        __syncthreads();
    }
    int run = lds[t] - s + chunk_off[b];
    #pragma unroll
    for (int j = 0; j < 4; ++j) {
        int i = base + j;
        if (i < n) row_ptr[i] = run;
        run += v[j];
    }
}

__global__ void scatter_kernel(const int* __restrict__ ei, int E, int N,
    const int* __restrict__ row_ptr, int* __restrict__ fill, int* __restrict__ src_sorted)
{
    int e = blockIdx.x * 256 + threadIdx.x;
    int src, dst;
    if (e < E)          { src = ei[e]; dst = ei[E + e]; }
    else if (e < E + N) { src = dst = e - E; }
    else return;
    int pos = row_ptr[dst] + atomicAdd(&fill[dst], 1);
    src_sorted[pos] = src;
}

// ---------------------------------------------------------------------------
// Layer-1 aggregation: one block per dst node, thread t=(h*32+c).
// Single pass: out = (sum_e w*h[src]) / (sum_e w);  z = relu(out + b1)
// (max-subtraction skipped: logits are tiny; softmax identical up to fp assoc.)
// ---------------------------------------------------------------------------
__global__ __launch_bounds__(256) void agg1_kernel(const float* __restrict__ h,
    const float* __restrict__ alpha_s, const float* __restrict__ alpha_d,
    const int* __restrict__ row_ptr, const int* __restrict__ src_sorted,
    const float* __restrict__ bias, float* __restrict__ z)
{
    const int i = blockIdx.x;
    const int t = threadIdx.x;
    const int hh = t >> 5;
    const int beg = row_ptr[i], end = row_ptr[i + 1];
    const float ad = alpha_d[(size_t)i * H_HEADS + hh];
    float acc = 0.f, dsum = 0.f;
    for (int p = beg; p < end; ++p) {
        int src = src_sorted[p];
        float e = alpha_s[(size_t)src * H_HEADS + hh] + ad;
        e = e > 0.f ? e : NEG_SLOPE * e;
        float w = __expf(e);
        acc = fmaf(w, h[(size_t)src * HC + t], acc);
        dsum += w;
    }
    float out = acc / (dsum + 1e-16f) + bias[t];
    z[(size_t)i * HC + t] = out > 0.f ? out : 0.f;
}

// ---------------------------------------------------------------------------
// Layer-2 aggregation fused with head-mean + b2 + Wp dot + sigmoid.
// ---------------------------------------------------------------------------
__global__ __launch_bounds__(256) void agg2_kernel(const float* __restrict__ h,
    const float* __restrict__ alpha_s, const float* __restrict__ alpha_d,
    const int* __restrict__ row_ptr, const int* __restrict__ src_sorted,
    const float* __restrict__ b2, const float* __restrict__ Wp,
    const float* __restrict__ bp, float* __restrict__ out)
{
    __shared__ float lds[256];
    const int i = blockIdx.x;
    const int t = threadIdx.x;
    const int hh = t >> 5;
    const int beg = row_ptr[i], end = row_ptr[i + 1];
    const float ad = alpha_d[(size_t)i * H_HEADS + hh];
    float acc = 0.f, dsum = 0.f;
    for (int p = beg; p < end; ++p) {
        int src = src_sorted[p];
        float e = alpha_s[(size_t)src * H_HEADS + hh] + ad;
        e = e > 0.f ? e : NEG_SLOPE * e;
        float w = __expf(e);
        acc = fmaf(w, h[(size_t)src * HC + t], acc);
        dsum += w;
    }
    lds[t] = acc / (dsum + 1e-16f);
    __syncthreads();
    if (t < 32) {
        float m = 0.f;
        #pragma unroll
        for (int q = 0; q < H_HEADS; ++q) m += lds[q * 32 + t];
        m = 0.125f * m + b2[t];
        float prod = m * Wp[t];
        #pragma unroll
        for (int off = 16; off > 0; off >>= 1) prod += __shfl_xor(prod, off);
        if (t == 0) out[i] = 1.f / (1.f + __expf(-(prod + bp[0])));
    }
}

// ---------------------------------------------------------------------------
extern "C" void kernel_launch(void* const* d_in, const int* in_sizes, int n_in,
                              void* d_out, int out_size, void* d_ws, size_t ws_size,
                              hipStream_t stream)
{
    const int*   ei  = (const int*)d_in[0];
    const float* x   = (const float*)d_in[1];
    const float* W1  = (const float*)d_in[2];
    const float* as1 = (const float*)d_in[3];
    const float* ad1 = (const float*)d_in[4];
    const float* b1  = (const float*)d_in[5];
    const float* W2  = (const float*)d_in[6];
    const float* as2 = (const float*)d_in[7];
    const float* ad2 = (const float*)d_in[8];
    const float* b2  = (const float*)d_in[9];
    const float* Wp  = (const float*)d_in[10];
    const float* bp  = (const float*)d_in[11];
    float* out = (float*)d_out;

    const int E = in_sizes[0] / 2;
    const int N = in_sizes[1] / F_IN;
    const int ET = E + N;

    // workspace layout
    float* h1  = (float*)d_ws;                       // N*256  (reused as h2)
    float* z1  = h1 + (size_t)N * HC;                // N*256
    float* asb = z1 + (size_t)N * HC;                // N*8
    float* adb = asb + (size_t)N * H_HEADS;          // N*8
    int* cnt       = (int*)(adb + (size_t)N * H_HEADS);  // N
    int* fill      = cnt + N;                        // N
    int* row_ptr   = fill + N;                       // N+1
    int* chunk_off = row_ptr + N + 1;                // 64
    int* chunk_sum = chunk_off + 64;                 // 64
    int* src_sorted = chunk_sum + 64;                // E+N
    float* h2 = h1;

    const int NCH = (N + 1023) / 1024;

    // ---- CSR build (by dst, self-loops included) ----
    zero_int<<<(2 * N + 255) / 256, 256, 0, stream>>>(cnt, 2 * N);
    hist_kernel<<<(ET + 255) / 256, 256, 0, stream>>>(ei, E, N, cnt);
    scan_sum<<<NCH, 256, 0, stream>>>(cnt, N, chunk_sum);
    scan_top<<<1, 64, 0, stream>>>(chunk_sum, NCH, chunk_off, row_ptr, N);
    scan_local<<<NCH, 256, 0, stream>>>(cnt, N, chunk_off, row_ptr);
    scatter_kernel<<<(ET + 255) / 256, 256, 0, stream>>>(ei, E, N, row_ptr, fill, src_sorted);

    // ---- Layer 1 ----
    dim3 g1((N + 63) / 64, HC / 64);
    gemm_tile<<<g1, 256, 0, stream>>>(x, W1, h1, N, F_IN, HC);
    alphas_kernel<<<N, 256, 0, stream>>>(h1, as1, ad1, asb, adb);
    agg1_kernel<<<N, 256, 0, stream>>>(h1, asb, adb, row_ptr, src_sorted, b1, z1);

    // ---- Layer 2 ----
    gemm_tile<<<g1, 256, 0, stream>>>(z1, W2, h2, N, HC, HC);
    alphas_kernel<<<N, 256, 0, stream>>>(h2, as2, ad2, asb, adb);
    agg2_kernel<<<N, 256, 0, stream>>>(h2, asb, adb, row_ptr, src_sorted, b2, Wp, bp, out);
}

// Round 2
// 845.563 us; speedup vs baseline: 1.1084x; 1.1084x over previous
//
#include <hip/hip_runtime.h>
#include <math.h>

#define H_HEADS 8
#define C_DIM   32
#define HC      256
#define F_IN    512
#define NEG_SLOPE 0.2f

typedef __attribute__((ext_vector_type(8))) short  bf16x8;
typedef __attribute__((ext_vector_type(4))) float  f32x4;
typedef __attribute__((ext_vector_type(2))) _Float16 h16x2;

__device__ __forceinline__ short f2bf(float f) {
    union { float f; unsigned u; } v; v.f = f;
    unsigned r = v.u + 0x7FFF + ((v.u >> 16) & 1);   // RNE
    return (short)(r >> 16);
}

// ---------------------------------------------------------------------------
// Repack W [K,256] fp32 -> MFMA B-frag-ordered bf16:
//   Wf[((s*16+nb)*64 + lane)*8 + j] = W[s*32 + (lane>>4)*8 + j][nb*16 + (lane&15)]
// so the GEMM's b_frag load is a fully coalesced 16B/lane read.
// ---------------------------------------------------------------------------
__global__ void wfrag_kernel(const float* __restrict__ W, short* __restrict__ Wf, int K)
{
    int tid = blockIdx.x * 256 + threadIdx.x;
    if (tid >= K * HC) return;
    int j  = tid & 7;
    int l  = (tid >> 3) & 63;
    int nb = (tid >> 9) & 15;
    int s  = tid >> 13;
    int k  = s * 32 + (l >> 4) * 8 + j;
    int n  = nb * 16 + (l & 15);
    Wf[tid] = f2bf(W[(size_t)k * HC + n]);
}

// ---------------------------------------------------------------------------
// MFMA GEMM: h16[M,256] = A[M,K] * W  (W pre-fragged bf16).
// Block=256 (4 waves), tile 64 rows x 256 cols; wave w owns rows w*16..+15.
// A fp32 (converted in-register) or bf16 per template. Output fp16.
// ---------------------------------------------------------------------------
template<bool ABF16>
__global__ __launch_bounds__(256) void gemm_mfma(const void* __restrict__ Aptr,
    const short* __restrict__ Bf, _Float16* __restrict__ h16, int M, int K)
{
    const int tid  = threadIdx.x;
    const int w    = tid >> 6;
    const int lane = tid & 63;
    const int quad = lane >> 4;
    const int ml   = lane & 15;
    const int bm   = blockIdx.x * 64;

    const int rowA  = bm + w * 16 + ml;
    const int rowL  = rowA < M ? rowA : M - 1;

    f32x4 acc[16];
    #pragma unroll
    for (int nb = 0; nb < 16; ++nb) acc[nb] = (f32x4){0.f, 0.f, 0.f, 0.f};

    const float* A32 = (const float*)Aptr;
    const short* A16 = (const short*)Aptr;
    const int nsteps = K >> 5;

    for (int s = 0; s < nsteps; ++s) {
        bf16x8 af;
        if (ABF16) {
            af = *(const bf16x8*)(A16 + (size_t)rowL * K + s * 32 + quad * 8);
        } else {
            const float* ap = A32 + (size_t)rowL * K + s * 32 + quad * 8;
            float4 a0 = *(const float4*)(ap);
            float4 a1 = *(const float4*)(ap + 4);
            af[0] = f2bf(a0.x); af[1] = f2bf(a0.y); af[2] = f2bf(a0.z); af[3] = f2bf(a0.w);
            af[4] = f2bf(a1.x); af[5] = f2bf(a1.y); af[6] = f2bf(a1.z); af[7] = f2bf(a1.w);
        }
        const short* bp = Bf + (size_t)(s * 16) * 512 + lane * 8;
        #pragma unroll
        for (int nb = 0; nb < 16; ++nb) {
            bf16x8 bf = *(const bf16x8*)(bp + nb * 512);
            acc[nb] = __builtin_amdgcn_mfma_f32_16x16x32_bf16(af, bf, acc[nb], 0, 0, 0);
        }
    }

    // C/D layout: col = nb*16 + (lane&15), row = w*16 + quad*4 + reg
    #pragma unroll
    for (int r = 0; r < 4; ++r) {
        int row = bm + w * 16 + quad * 4 + r;
        if (row < M) {
            #pragma unroll
            for (int nb = 0; nb < 16; ++nb)
                h16[(size_t)row * HC + nb * 16 + ml] = (_Float16)acc[nb][r];
        }
    }
}

// ---------------------------------------------------------------------------
// alpha_s[n,h] = sum_c h[n,h,c]*a_s[h,c]; same for a_d. One block per node.
// ---------------------------------------------------------------------------
__global__ __launch_bounds__(256) void alphas_kernel(const _Float16* __restrict__ h16,
    const float* __restrict__ a_s, const float* __restrict__ a_d,
    float* __restrict__ alpha_s, float* __restrict__ alpha_d)
{
    const int n = blockIdx.x;
    const int t = threadIdx.x;
    float v = (float)h16[(size_t)n * HC + t];
    float ps = v * a_s[t];
    float pd = v * a_d[t];
    #pragma unroll
    for (int off = 16; off > 0; off >>= 1) {
        ps += __shfl_xor(ps, off);
        pd += __shfl_xor(pd, off);
    }
    if ((t & 31) == 0) {
        int hh = t >> 5;
        alpha_s[(size_t)n * H_HEADS + hh] = ps;
        alpha_d[(size_t)n * H_HEADS + hh] = pd;
    }
}

// ---------------------------------------------------------------------------
// CSR build
// ---------------------------------------------------------------------------
__global__ void zero_int(int* __restrict__ p, int n)
{
    int i = blockIdx.x * 256 + threadIdx.x;
    if (i < n) p[i] = 0;
}

__global__ void hist_kernel(const int* __restrict__ ei, int E, int N,
                            int* __restrict__ cnt)
{
    int e = blockIdx.x * 256 + threadIdx.x;
    if (e < E) atomicAdd(&cnt[ei[E + e]], 1);
    else if (e < E + N) atomicAdd(&cnt[e - E], 1);
}

__global__ __launch_bounds__(256) void scan_sum(const int* __restrict__ cnt, int n,
                                                int* __restrict__ chunk_sum)
{
    __shared__ int lds[256];
    int b = blockIdx.x, t = threadIdx.x;
    int base = b * 1024 + t * 4;
    int s = 0;
    #pragma unroll
    for (int j = 0; j < 4; ++j) { int i = base + j; if (i < n) s += cnt[i]; }
    lds[t] = s; __syncthreads();
    for (int off = 128; off > 0; off >>= 1) {
        if (t < off) lds[t] += lds[t + off];
        __syncthreads();
    }
    if (t == 0) chunk_sum[b] = lds[0];
}

__global__ void scan_top(const int* __restrict__ chunk_sum, int nch,
                         int* __restrict__ chunk_off, int* __restrict__ row_ptr,
                         int n_nodes)
{
    int t = threadIdx.x;
    int v = (t < nch) ? chunk_sum[t] : 0;
    int inc = v;
    #pragma unroll
    for (int off = 1; off < 64; off <<= 1) {
        int u = __shfl_up(inc, off);
        if (t >= off) inc += u;
    }
    if (t < nch) chunk_off[t] = inc - v;
    if (t == 63) row_ptr[n_nodes] = inc;
}

__global__ __launch_bounds__(256) void scan_local(const int* __restrict__ cnt, int n,
    const int* __restrict__ chunk_off, int* __restrict__ row_ptr)
{
    __shared__ int lds[256];
    int b = blockIdx.x, t = threadIdx.x;
    int base = b * 1024 + t * 4;
    int v[4]; int s = 0;
    #pragma unroll
    for (int j = 0; j < 4; ++j) { int i = base + j; v[j] = (i < n) ? cnt[i] : 0; s += v[j]; }
    lds[t] = s; __syncthreads();
    for (int off = 1; off < 256; off <<= 1) {
        int u = (t >= off) ? lds[t - off] : 0;
        __syncthreads();
        lds[t] += u;
        __syncthreads();
    }
    int run = lds[t] - s + chunk_off[b];
    #pragma unroll
    for (int j = 0; j < 4; ++j) {
        int i = base + j;
        if (i < n) row_ptr[i] = run;
        run += v[j];
    }
}

__global__ void scatter_kernel(const int* __restrict__ ei, int E, int N,
    const int* __restrict__ row_ptr, int* __restrict__ fill, int* __restrict__ src_sorted)
{
    int e = blockIdx.x * 256 + threadIdx.x;
    int src, dst;
    if (e < E)          { src = ei[e]; dst = ei[E + e]; }
    else if (e < E + N) { src = dst = e - E; }
    else return;
    int pos = row_ptr[dst] + atomicAdd(&fill[dst], 1);
    src_sorted[pos] = src;
}

// ---------------------------------------------------------------------------
// Layer-1 aggregation. Block=256 per dst node: two 128-lane groups process
// alternate edges; lane l covers channels 2l,2l+1 via half2 gather.
// z written in bf16 (input to layer-2 GEMM).
// ---------------------------------------------------------------------------
__global__ __launch_bounds__(256) void agg1_kernel(const _Float16* __restrict__ h16,
    const float* __restrict__ alpha_s, const float* __restrict__ alpha_d,
    const int* __restrict__ row_ptr, const int* __restrict__ src_sorted,
    const float* __restrict__ bias, short* __restrict__ z_bf)
{
    __shared__ float2 accs[128];
    __shared__ float  dsums[H_HEADS];
    const int i = blockIdx.x;
    const int t = threadIdx.x;
    const int g = t >> 7, l = t & 127;
    const int hh = l >> 4;
    const int beg = row_ptr[i], end = row_ptr[i + 1];
    const float ad = alpha_d[(size_t)i * H_HEADS + hh];
    float2 acc = {0.f, 0.f};
    float dsum = 0.f;
    for (int p = beg + g; p < end; p += 2) {
        int src = src_sorted[p];
        float e = alpha_s[(size_t)src * H_HEADS + hh] + ad;
        e = e > 0.f ? e : NEG_SLOPE * e;
        float w = __expf(e);
        h16x2 hv = *(const h16x2*)(h16 + (size_t)src * HC + 2 * l);
        acc.x = fmaf(w, (float)hv.x, acc.x);
        acc.y = fmaf(w, (float)hv.y, acc.y);
        dsum += w;
    }
    if (g == 0) {
        accs[l] = acc;
        if ((l & 15) == 0) dsums[hh] = dsum;
    }
    __syncthreads();
    if (g == 1) {
        float2 o = accs[l];
        float inv = 1.f / (dsum + dsums[hh] + 1e-16f);
        float z0 = (acc.x + o.x) * inv + bias[2 * l];
        float z1 = (acc.y + o.y) * inv + bias[2 * l + 1];
        z0 = z0 > 0.f ? z0 : 0.f;
        z1 = z1 > 0.f ? z1 : 0.f;
        unsigned pk = (unsigned)(unsigned short)f2bf(z0) |
                      ((unsigned)(unsigned short)f2bf(z1) << 16);
        *(unsigned*)(z_bf + (size_t)i * HC + 2 * l) = pk;
    }
}

// ---------------------------------------------------------------------------
// Layer-2 aggregation fused with head-mean + b2 + Wp dot + sigmoid.
// ---------------------------------------------------------------------------
__global__ __launch_bounds__(256) void agg2_kernel(const _Float16* __restrict__ h16,
    const float* __restrict__ alpha_s, const float* __restrict__ alpha_d,
    const int* __restrict__ row_ptr, const int* __restrict__ src_sorted,
    const float* __restrict__ b2, const float* __restrict__ Wp,
    const float* __restrict__ bp, float* __restrict__ out)
{
    __shared__ float2 accs[128];
    __shared__ float  dsums[H_HEADS];
    __shared__ float2 fin[128];
    const int i = blockIdx.x;
    const int t = threadIdx.x;
    const int g = t >> 7, l = t & 127;
    const int hh = l >> 4;
    const int beg = row_ptr[i], end = row_ptr[i + 1];
    const float ad = alpha_d[(size_t)i * H_HEADS + hh];
    float2 acc = {0.f, 0.f};
    float dsum = 0.f;
    for (int p = beg + g; p < end; p += 2) {
        int src = src_sorted[p];
        float e = alpha_s[(size_t)src * H_HEADS + hh] + ad;
        e = e > 0.f ? e : NEG_SLOPE * e;
        float w = __expf(e);
        h16x2 hv = *(const h16x2*)(h16 + (size_t)src * HC + 2 * l);
        acc.x = fmaf(w, (float)hv.x, acc.x);
        acc.y = fmaf(w, (float)hv.y, acc.y);
        dsum += w;
    }
    if (g == 0) {
        accs[l] = acc;
        if ((l & 15) == 0) dsums[hh] = dsum;
    }
    __syncthreads();
    if (g == 1) {
        float2 o = accs[l];
        float inv = 1.f / (dsum + dsums[hh] + 1e-16f);
        fin[l] = make_float2((acc.x + o.x) * inv, (acc.y + o.y) * inv);
    }
    __syncthreads();
    if (t < 16) {
        float2 s = {0.f, 0.f};
        #pragma unroll
        for (int q = 0; q < H_HEADS; ++q) {
            float2 v = fin[q * 16 + t];
            s.x += v.x; s.y += v.y;
        }
        float m0 = 0.125f * s.x + b2[2 * t];
        float m1 = 0.125f * s.y + b2[2 * t + 1];
        float prod = m0 * Wp[2 * t] + m1 * Wp[2 * t + 1];
        #pragma unroll
        for (int off = 8; off > 0; off >>= 1) prod += __shfl_xor(prod, off);
        if (t == 0) out[i] = 1.f / (1.f + __expf(-(prod + bp[0])));
    }
}

// ---------------------------------------------------------------------------
extern "C" void kernel_launch(void* const* d_in, const int* in_sizes, int n_in,
                              void* d_out, int out_size, void* d_ws, size_t ws_size,
                              hipStream_t stream)
{
    const int*   ei  = (const int*)d_in[0];
    const float* x   = (const float*)d_in[1];
    const float* W1  = (const float*)d_in[2];
    const float* as1 = (const float*)d_in[3];
    const float* ad1 = (const float*)d_in[4];
    const float* b1  = (const float*)d_in[5];
    const float* W2  = (const float*)d_in[6];
    const float* as2 = (const float*)d_in[7];
    const float* ad2 = (const float*)d_in[8];
    const float* b2  = (const float*)d_in[9];
    const float* Wp  = (const float*)d_in[10];
    const float* bp  = (const float*)d_in[11];
    float* out = (float*)d_out;

    const int E = in_sizes[0] / 2;
    const int N = in_sizes[1] / F_IN;
    const int ET = E + N;

    // workspace layout (all section sizes multiples of 16B)
    float*    asb = (float*)d_ws;                          // N*8
    float*    adb = asb + (size_t)N * H_HEADS;             // N*8
    _Float16* h16 = (_Float16*)(adb + (size_t)N * H_HEADS);// N*256 (layer1+2)
    short*    z1b = (short*)(h16 + (size_t)N * HC);        // N*256 bf16
    short*    Wf1 = z1b + (size_t)N * HC;                  // 512*256
    short*    Wf2 = Wf1 + (size_t)F_IN * HC;               // 256*256
    int* cnt       = (int*)(Wf2 + (size_t)HC * HC);        // N
    int* fill      = cnt + N;                              // N
    int* row_ptr   = fill + N;                             // N+1
    int* chunk_off = row_ptr + N + 1;                      // 64
    int* chunk_sum = chunk_off + 64;                       // 64
    int* src_sorted = chunk_sum + 64;                      // E+N

    const int NCH = (N + 1023) / 1024;
    const int MB  = (N + 63) / 64;

    // ---- CSR build (by dst, self-loops included) ----
    zero_int<<<(2 * N + 255) / 256, 256, 0, stream>>>(cnt, 2 * N);
    hist_kernel<<<(ET + 255) / 256, 256, 0, stream>>>(ei, E, N, cnt);
    scan_sum<<<NCH, 256, 0, stream>>>(cnt, N, chunk_sum);
    scan_top<<<1, 64, 0, stream>>>(chunk_sum, NCH, chunk_off, row_ptr, N);
    scan_local<<<NCH, 256, 0, stream>>>(cnt, N, chunk_off, row_ptr);
    scatter_kernel<<<(ET + 255) / 256, 256, 0, stream>>>(ei, E, N, row_ptr, fill, src_sorted);

    // ---- W repack (frag-ordered bf16) ----
    wfrag_kernel<<<(F_IN * HC + 255) / 256, 256, 0, stream>>>(W1, Wf1, F_IN);
    wfrag_kernel<<<(HC * HC + 255) / 256, 256, 0, stream>>>(W2, Wf2, HC);

    // ---- Layer 1 ----
    gemm_mfma<false><<<MB, 256, 0, stream>>>(x, Wf1, h16, N, F_IN);
    alphas_kernel<<<N, 256, 0, stream>>>(h16, as1, ad1, asb, adb);
    agg1_kernel<<<N, 256, 0, stream>>>(h16, asb, adb, row_ptr, src_sorted, b1, z1b);

    // ---- Layer 2 ----
    gemm_mfma<true><<<MB, 256, 0, stream>>>(z1b, Wf2, h16, N, HC);
    alphas_kernel<<<N, 256, 0, stream>>>(h16, as2, ad2, asb, adb);
    agg2_kernel<<<N, 256, 0, stream>>>(h16, asb, adb, row_ptr, src_sorted, b2, Wp, bp, out);
}

// Round 3
// 620.453 us; speedup vs baseline: 1.5106x; 1.3628x over previous
//
#include <hip/hip_runtime.h>
#include <math.h>

#define H_HEADS 8
#define C_DIM   32
#define HC      256
#define F_IN    512
#define NEG_SLOPE 0.2f

typedef __attribute__((ext_vector_type(8))) short  bf16x8;
typedef __attribute__((ext_vector_type(4))) short  s16x4;
typedef __attribute__((ext_vector_type(4))) float  f32x4;
typedef __attribute__((ext_vector_type(4))) _Float16 h16x4;

__device__ __forceinline__ short f2bf(float f) {
    union { float f; unsigned u; } v; v.f = f;
    unsigned r = v.u + 0x7FFF + ((v.u >> 16) & 1);   // RNE
    return (short)(r >> 16);
}

// ---------------------------------------------------------------------------
// Repack W [K,256] fp32 -> MFMA B-frag-ordered bf16.
// ---------------------------------------------------------------------------
__global__ void wfrag_kernel(const float* __restrict__ W, short* __restrict__ Wf, int K)
{
    int tid = blockIdx.x * 256 + threadIdx.x;
    if (tid >= K * HC) return;
    int j  = tid & 7;
    int l  = (tid >> 3) & 63;
    int nb = (tid >> 9) & 15;
    int s  = tid >> 13;
    int k  = s * 32 + (l >> 4) * 8 + j;
    int n  = nb * 16 + (l & 15);
    Wf[tid] = f2bf(W[(size_t)k * HC + n]);
}

// ---------------------------------------------------------------------------
// MFMA GEMM: h16[M,256] = A[M,K] * W (pre-fragged bf16). 64-row tile, 4 waves.
// Explicit software prefetch of next K-step's A fragment.
// ---------------------------------------------------------------------------
template<bool ABF16>
__global__ __launch_bounds__(256) void gemm_mfma(const void* __restrict__ Aptr,
    const short* __restrict__ Bf, _Float16* __restrict__ h16, int M, int K)
{
    const int tid  = threadIdx.x;
    const int w    = tid >> 6;
    const int lane = tid & 63;
    const int quad = lane >> 4;
    const int ml   = lane & 15;
    const int bm   = blockIdx.x * 64;

    const int rowA = bm + w * 16 + ml;
    const int rowL = rowA < M ? rowA : M - 1;

    f32x4 acc[16];
    #pragma unroll
    for (int nb = 0; nb < 16; ++nb) acc[nb] = (f32x4){0.f, 0.f, 0.f, 0.f};

    const float* A32 = (const float*)Aptr;
    const short* A16 = (const short*)Aptr;
    const int nsteps = K >> 5;

    float4 p0, p1;          // fp32 prefetch regs
    bf16x8 pb;              // bf16 prefetch reg
    if (ABF16) {
        pb = *(const bf16x8*)(A16 + (size_t)rowL * K + quad * 8);
    } else {
        const float* ap = A32 + (size_t)rowL * K + quad * 8;
        p0 = *(const float4*)(ap);
        p1 = *(const float4*)(ap + 4);
    }

    for (int s = 0; s < nsteps; ++s) {
        bf16x8 af;
        if (ABF16) {
            af = pb;
            if (s + 1 < nsteps)
                pb = *(const bf16x8*)(A16 + (size_t)rowL * K + (s + 1) * 32 + quad * 8);
        } else {
            af[0] = f2bf(p0.x); af[1] = f2bf(p0.y); af[2] = f2bf(p0.z); af[3] = f2bf(p0.w);
            af[4] = f2bf(p1.x); af[5] = f2bf(p1.y); af[6] = f2bf(p1.z); af[7] = f2bf(p1.w);
            if (s + 1 < nsteps) {
                const float* ap = A32 + (size_t)rowL * K + (s + 1) * 32 + quad * 8;
                p0 = *(const float4*)(ap);
                p1 = *(const float4*)(ap + 4);
            }
        }
        const short* bp = Bf + (size_t)(s * 16) * 512 + lane * 8;
        #pragma unroll
        for (int nb = 0; nb < 16; ++nb) {
            bf16x8 bf = *(const bf16x8*)(bp + nb * 512);
            acc[nb] = __builtin_amdgcn_mfma_f32_16x16x32_bf16(af, bf, acc[nb], 0, 0, 0);
        }
    }

    #pragma unroll
    for (int r = 0; r < 4; ++r) {
        int row = bm + w * 16 + quad * 4 + r;
        if (row < M) {
            #pragma unroll
            for (int nb = 0; nb < 16; ++nb)
                h16[(size_t)row * HC + nb * 16 + ml] = (_Float16)acc[nb][r];
        }
    }
}

// ---------------------------------------------------------------------------
// alpha_s[n,h] = sum_c h[n,h,c]*a_s[h,c]; same for a_d.
// ---------------------------------------------------------------------------
__global__ __launch_bounds__(256) void alphas_kernel(const _Float16* __restrict__ h16,
    const float* __restrict__ a_s, const float* __restrict__ a_d,
    float* __restrict__ alpha_s, float* __restrict__ alpha_d)
{
    const int n = blockIdx.x;
    const int t = threadIdx.x;
    float v = (float)h16[(size_t)n * HC + t];
    float ps = v * a_s[t];
    float pd = v * a_d[t];
    #pragma unroll
    for (int off = 16; off > 0; off >>= 1) {
        ps += __shfl_xor(ps, off);
        pd += __shfl_xor(pd, off);
    }
    if ((t & 31) == 0) {
        int hh = t >> 5;
        alpha_s[(size_t)n * H_HEADS + hh] = ps;
        alpha_d[(size_t)n * H_HEADS + hh] = pd;
    }
}

// ---------------------------------------------------------------------------
// Per-edge softmax weights: w[p,h] = exp(leaky(alpha_s[src]+alpha_d[dst])).
// Edge-parallel, fully latency-tolerant.
// ---------------------------------------------------------------------------
__global__ __launch_bounds__(256) void wcalc_kernel(const int* __restrict__ src_sorted,
    const int* __restrict__ dst_sorted, const float* __restrict__ alpha_s,
    const float* __restrict__ alpha_d, float* __restrict__ wq, int P)
{
    int p = blockIdx.x * 256 + threadIdx.x;
    if (p >= P) return;
    int s = src_sorted[p], d = dst_sorted[p];
    const float4* as = (const float4*)(alpha_s + (size_t)s * H_HEADS);
    const float4* ad = (const float4*)(alpha_d + (size_t)d * H_HEADS);
    float4 s0 = as[0], s1 = as[1], d0 = ad[0], d1 = ad[1];
    float e[8] = {s0.x + d0.x, s0.y + d0.y, s0.z + d0.z, s0.w + d0.w,
                  s1.x + d1.x, s1.y + d1.y, s1.z + d1.z, s1.w + d1.w};
    float4 o0, o1;
    float* o = (float*)&o0;
    #pragma unroll
    for (int h = 0; h < 8; ++h) {
        float v = e[h] > 0.f ? e[h] : NEG_SLOPE * e[h];
        ((float*)&o0)[h < 4 ? h : 0] = 0.f;  // placate compiler; overwritten below
        (h < 4 ? ((float*)&o0)[h] : ((float*)&o1)[h - 4]) = __expf(v);
    }
    float4* op = (float4*)(wq + (size_t)p * H_HEADS);
    op[0] = o0; op[1] = o1;
}

// ---------------------------------------------------------------------------
// CSR build
// ---------------------------------------------------------------------------
__global__ void zero_int(int* __restrict__ p, int n)
{
    int i = blockIdx.x * 256 + threadIdx.x;
    if (i < n) p[i] = 0;
}

__global__ void hist_kernel(const int* __restrict__ ei, int E, int N,
                            int* __restrict__ cnt)
{
    int e = blockIdx.x * 256 + threadIdx.x;
    if (e < E) atomicAdd(&cnt[ei[E + e]], 1);
    else if (e < E + N) atomicAdd(&cnt[e - E], 1);
}

__global__ __launch_bounds__(256) void scan_sum(const int* __restrict__ cnt, int n,
                                                int* __restrict__ chunk_sum)
{
    __shared__ int lds[256];
    int b = blockIdx.x, t = threadIdx.x;
    int base = b * 1024 + t * 4;
    int s = 0;
    #pragma unroll
    for (int j = 0; j < 4; ++j) { int i = base + j; if (i < n) s += cnt[i]; }
    lds[t] = s; __syncthreads();
    for (int off = 128; off > 0; off >>= 1) {
        if (t < off) lds[t] += lds[t + off];
        __syncthreads();
    }
    if (t == 0) chunk_sum[b] = lds[0];
}

__global__ void scan_top(const int* __restrict__ chunk_sum, int nch,
                         int* __restrict__ chunk_off, int* __restrict__ row_ptr,
                         int n_nodes)
{
    int t = threadIdx.x;
    int v = (t < nch) ? chunk_sum[t] : 0;
    int inc = v;
    #pragma unroll
    for (int off = 1; off < 64; off <<= 1) {
        int u = __shfl_up(inc, off);
        if (t >= off) inc += u;
    }
    if (t < nch) chunk_off[t] = inc - v;
    if (t == 63) row_ptr[n_nodes] = inc;
}

__global__ __launch_bounds__(256) void scan_local(const int* __restrict__ cnt, int n,
    const int* __restrict__ chunk_off, int* __restrict__ row_ptr)
{
    __shared__ int lds[256];
    int b = blockIdx.x, t = threadIdx.x;
    int base = b * 1024 + t * 4;
    int v[4]; int s = 0;
    #pragma unroll
    for (int j = 0; j < 4; ++j) { int i = base + j; v[j] = (i < n) ? cnt[i] : 0; s += v[j]; }
    lds[t] = s; __syncthreads();
    for (int off = 1; off < 256; off <<= 1) {
        int u = (t >= off) ? lds[t - off] : 0;
        __syncthreads();
        lds[t] += u;
        __syncthreads();
    }
    int run = lds[t] - s + chunk_off[b];
    #pragma unroll
    for (int j = 0; j < 4; ++j) {
        int i = base + j;
        if (i < n) row_ptr[i] = run;
        run += v[j];
    }
}

__global__ void scatter_kernel(const int* __restrict__ ei, int E, int N,
    const int* __restrict__ row_ptr, int* __restrict__ fill,
    int* __restrict__ src_sorted, int* __restrict__ dst_sorted)
{
    int e = blockIdx.x * 256 + threadIdx.x;
    int src, dst;
    if (e < E)          { src = ei[e]; dst = ei[E + e]; }
    else if (e < E + N) { src = dst = e - E; }
    else return;
    int pos = row_ptr[dst] + atomicAdd(&fill[dst], 1);
    src_sorted[pos] = src;
    dst_sorted[pos] = dst;
}

// ---------------------------------------------------------------------------
// Layer-1 aggregation: ONE WAVE per dst node. Lane l owns channels 4l..4l+3
// (8B h-gather -> 512B/row per wave). Edge loop unrolled x4 for MLP.
// ---------------------------------------------------------------------------
__global__ __launch_bounds__(256) void agg1_kernel(const _Float16* __restrict__ h16,
    const float* __restrict__ wq, const int* __restrict__ row_ptr,
    const int* __restrict__ src_sorted, const float* __restrict__ bias,
    short* __restrict__ z_bf, int N)
{
    const int l = threadIdx.x & 63;
    const int i = blockIdx.x * 4 + (threadIdx.x >> 6);
    if (i >= N) return;
    const int hh = l >> 3;
    const int beg = row_ptr[i], end = row_ptr[i + 1];
    f32x4 acc = {0.f, 0.f, 0.f, 0.f};
    float dsum = 0.f;
    int p = beg;
    for (; p + 3 < end; p += 4) {
        int s0 = src_sorted[p], s1 = src_sorted[p + 1];
        int s2 = src_sorted[p + 2], s3 = src_sorted[p + 3];
        float w0 = wq[(size_t)p * 8 + hh];
        float w1 = wq[(size_t)(p + 1) * 8 + hh];
        float w2 = wq[(size_t)(p + 2) * 8 + hh];
        float w3 = wq[(size_t)(p + 3) * 8 + hh];
        h16x4 v0 = *(const h16x4*)(h16 + (size_t)s0 * HC + 4 * l);
        h16x4 v1 = *(const h16x4*)(h16 + (size_t)s1 * HC + 4 * l);
        h16x4 v2 = *(const h16x4*)(h16 + (size_t)s2 * HC + 4 * l);
        h16x4 v3 = *(const h16x4*)(h16 + (size_t)s3 * HC + 4 * l);
        #pragma unroll
        for (int j = 0; j < 4; ++j) {
            acc[j] = fmaf(w0, (float)v0[j], acc[j]);
            acc[j] = fmaf(w1, (float)v1[j], acc[j]);
            acc[j] = fmaf(w2, (float)v2[j], acc[j]);
            acc[j] = fmaf(w3, (float)v3[j], acc[j]);
        }
        dsum += (w0 + w1) + (w2 + w3);
    }
    for (; p < end; ++p) {
        int s0 = src_sorted[p];
        float w0 = wq[(size_t)p * 8 + hh];
        h16x4 v0 = *(const h16x4*)(h16 + (size_t)s0 * HC + 4 * l);
        #pragma unroll
        for (int j = 0; j < 4; ++j) acc[j] = fmaf(w0, (float)v0[j], acc[j]);
        dsum += w0;
    }
    float inv = 1.f / (dsum + 1e-16f);
    s16x4 pk;
    #pragma unroll
    for (int j = 0; j < 4; ++j) {
        float z = acc[j] * inv + bias[4 * l + j];
        pk[j] = f2bf(z > 0.f ? z : 0.f);
    }
    *(s16x4*)(z_bf + (size_t)i * HC + 4 * l) = pk;
}

// ---------------------------------------------------------------------------
// Layer-2 aggregation fused with head-mean + b2 + Wp dot + sigmoid.
// Wave per node; full-wave shuffle reduction in epilogue.
// ---------------------------------------------------------------------------
__global__ __launch_bounds__(256) void agg2_kernel(const _Float16* __restrict__ h16,
    const float* __restrict__ wq, const int* __restrict__ row_ptr,
    const int* __restrict__ src_sorted, const float* __restrict__ b2,
    const float* __restrict__ Wp, const float* __restrict__ bp,
    float* __restrict__ out, int N)
{
    const int l = threadIdx.x & 63;
    const int i = blockIdx.x * 4 + (threadIdx.x >> 6);
    if (i >= N) return;
    const int hh = l >> 3;
    const int beg = row_ptr[i], end = row_ptr[i + 1];
    f32x4 acc = {0.f, 0.f, 0.f, 0.f};
    float dsum = 0.f;
    int p = beg;
    for (; p + 3 < end; p += 4) {
        int s0 = src_sorted[p], s1 = src_sorted[p + 1];
        int s2 = src_sorted[p + 2], s3 = src_sorted[p + 3];
        float w0 = wq[(size_t)p * 8 + hh];
        float w1 = wq[(size_t)(p + 1) * 8 + hh];
        float w2 = wq[(size_t)(p + 2) * 8 + hh];
        float w3 = wq[(size_t)(p + 3) * 8 + hh];
        h16x4 v0 = *(const h16x4*)(h16 + (size_t)s0 * HC + 4 * l);
        h16x4 v1 = *(const h16x4*)(h16 + (size_t)s1 * HC + 4 * l);
        h16x4 v2 = *(const h16x4*)(h16 + (size_t)s2 * HC + 4 * l);
        h16x4 v3 = *(const h16x4*)(h16 + (size_t)s3 * HC + 4 * l);
        #pragma unroll
        for (int j = 0; j < 4; ++j) {
            acc[j] = fmaf(w0, (float)v0[j], acc[j]);
            acc[j] = fmaf(w1, (float)v1[j], acc[j]);
            acc[j] = fmaf(w2, (float)v2[j], acc[j]);
            acc[j] = fmaf(w3, (float)v3[j], acc[j]);
        }
        dsum += (w0 + w1) + (w2 + w3);
    }
    for (; p < end; ++p) {
        int s0 = src_sorted[p];
        float w0 = wq[(size_t)p * 8 + hh];
        h16x4 v0 = *(const h16x4*)(h16 + (size_t)s0 * HC + 4 * l);
        #pragma unroll
        for (int j = 0; j < 4; ++j) acc[j] = fmaf(w0, (float)v0[j], acc[j]);
        dsum += w0;
    }
    float inv = 1.f / (dsum + 1e-16f);
    int cc = (4 * l) & 31;             // channel-within-head
    float partial = 0.f;
    #pragma unroll
    for (int j = 0; j < 4; ++j) partial = fmaf(acc[j] * inv, Wp[cc + j], partial);
    if (l < 8) {
        #pragma unroll
        for (int j = 0; j < 4; ++j) partial = fmaf(8.f * b2[4 * l + j], Wp[4 * l + j], partial);
    }
    #pragma unroll
    for (int off = 32; off > 0; off >>= 1) partial += __shfl_xor(partial, off);
    if (l == 0) out[i] = 1.f / (1.f + __expf(-(0.125f * partial + bp[0])));
}

// ---------------------------------------------------------------------------
extern "C" void kernel_launch(void* const* d_in, const int* in_sizes, int n_in,
                              void* d_out, int out_size, void* d_ws, size_t ws_size,
                              hipStream_t stream)
{
    const int*   ei  = (const int*)d_in[0];
    const float* x   = (const float*)d_in[1];
    const float* W1  = (const float*)d_in[2];
    const float* as1 = (const float*)d_in[3];
    const float* ad1 = (const float*)d_in[4];
    const float* b1  = (const float*)d_in[5];
    const float* W2  = (const float*)d_in[6];
    const float* as2 = (const float*)d_in[7];
    const float* ad2 = (const float*)d_in[8];
    const float* b2  = (const float*)d_in[9];
    const float* Wp  = (const float*)d_in[10];
    const float* bp  = (const float*)d_in[11];
    float* out = (float*)d_out;

    const int E = in_sizes[0] / 2;
    const int N = in_sizes[1] / F_IN;
    const int ET = E + N;

    // workspace layout
    float*    asb = (float*)d_ws;                          // N*8
    float*    adb = asb + (size_t)N * H_HEADS;             // N*8
    _Float16* h16 = (_Float16*)(adb + (size_t)N * H_HEADS);// N*256
    short*    z1b = (short*)(h16 + (size_t)N * HC);        // N*256 bf16
    short*    Wf1 = z1b + (size_t)N * HC;                  // 512*256
    short*    Wf2 = Wf1 + (size_t)F_IN * HC;               // 256*256
    float*    wq  = (float*)(Wf2 + (size_t)HC * HC);       // (E+N)*8
    int* cnt       = (int*)(wq + (size_t)ET * H_HEADS);    // N
    int* fill      = cnt + N;                              // N
    int* row_ptr   = fill + N;                             // N+1
    int* chunk_off = row_ptr + N + 1;                      // 64
    int* chunk_sum = chunk_off + 64;                       // 64
    int* src_sorted = chunk_sum + 64;                      // E+N
    int* dst_sorted = src_sorted + ET;                     // E+N

    const int NCH = (N + 1023) / 1024;
    const int MB  = (N + 63) / 64;
    const int NB4 = (N + 3) / 4;

    // ---- CSR build ----
    zero_int<<<(2 * N + 255) / 256, 256, 0, stream>>>(cnt, 2 * N);
    hist_kernel<<<(ET + 255) / 256, 256, 0, stream>>>(ei, E, N, cnt);
    scan_sum<<<NCH, 256, 0, stream>>>(cnt, N, chunk_sum);
    scan_top<<<1, 64, 0, stream>>>(chunk_sum, NCH, chunk_off, row_ptr, N);
    scan_local<<<NCH, 256, 0, stream>>>(cnt, N, chunk_off, row_ptr);
    scatter_kernel<<<(ET + 255) / 256, 256, 0, stream>>>(ei, E, N, row_ptr, fill,
                                                         src_sorted, dst_sorted);

    // ---- W repack ----
    wfrag_kernel<<<(F_IN * HC + 255) / 256, 256, 0, stream>>>(W1, Wf1, F_IN);
    wfrag_kernel<<<(HC * HC + 255) / 256, 256, 0, stream>>>(W2, Wf2, HC);

    // ---- Layer 1 ----
    gemm_mfma<false><<<MB, 256, 0, stream>>>(x, Wf1, h16, N, F_IN);
    alphas_kernel<<<N, 256, 0, stream>>>(h16, as1, ad1, asb, adb);
    wcalc_kernel<<<(ET + 255) / 256, 256, 0, stream>>>(src_sorted, dst_sorted, asb, adb, wq, ET);
    agg1_kernel<<<NB4, 256, 0, stream>>>(h16, wq, row_ptr, src_sorted, b1, z1b, N);

    // ---- Layer 2 ----
    gemm_mfma<true><<<MB, 256, 0, stream>>>(z1b, Wf2, h16, N, HC);
    alphas_kernel<<<N, 256, 0, stream>>>(h16, as2, ad2, asb, adb);
    wcalc_kernel<<<(ET + 255) / 256, 256, 0, stream>>>(src_sorted, dst_sorted, asb, adb, wq, ET);
    agg2_kernel<<<NB4, 256, 0, stream>>>(h16, wq, row_ptr, src_sorted, b2, Wp, bp, out, N);
}

// Round 4
// 503.622 us; speedup vs baseline: 1.8610x; 1.2320x over previous
//
#include <hip/hip_runtime.h>
#include <math.h>

#define H_HEADS 8
#define C_DIM   32
#define HC      256
#define F_IN    512
#define NEG_SLOPE 0.2f

typedef __attribute__((ext_vector_type(8))) short  bf16x8;
typedef __attribute__((ext_vector_type(4))) short  s16x4;
typedef __attribute__((ext_vector_type(4))) float  f32x4;
typedef __attribute__((ext_vector_type(4))) _Float16 h16x4;

__device__ __forceinline__ short f2bf(float f) {
    union { float f; unsigned u; } v; v.f = f;
    unsigned r = v.u + 0x7FFF + ((v.u >> 16) & 1);   // RNE
    return (short)(r >> 16);
}

__device__ __forceinline__ void gl2lds16(const short* g, short* l) {
    __builtin_amdgcn_global_load_lds(
        (const __attribute__((address_space(1))) void*)g,
        (__attribute__((address_space(3))) void*)l, 16, 0, 0);
}

// ---------------------------------------------------------------------------
// Repack W [K,256] fp32 -> MFMA B-frag-ordered bf16. One K-step (32 rows) of
// fragments = 8192 shorts = 16 KB, contiguous -> LDS-stageable.
// ---------------------------------------------------------------------------
__global__ void wfrag_kernel(const float* __restrict__ W, short* __restrict__ Wf, int K)
{
    int tid = blockIdx.x * 256 + threadIdx.x;
    if (tid >= K * HC) return;
    int j  = tid & 7;
    int l  = (tid >> 3) & 63;
    int nb = (tid >> 9) & 15;
    int s  = tid >> 13;
    int k  = s * 32 + (l >> 4) * 8 + j;
    int n  = nb * 16 + (l & 15);
    Wf[tid] = f2bf(W[(size_t)k * HC + n]);
}

// ---------------------------------------------------------------------------
// MFMA GEMM: h16[M,256] = A[M,K] * W (pre-fragged bf16).
// 64-row x 256-col tile, 4 waves. B staged global->LDS (async, double-buffered,
// one barrier per K-step); each block fetches B once (vs once per wave).
// A: register prefetch, fp32 (in-reg cvt) or bf16 per template.
// ---------------------------------------------------------------------------
template<bool ABF16>
__global__ __launch_bounds__(256) void gemm_mfma(const void* __restrict__ Aptr,
    const short* __restrict__ Bf, _Float16* __restrict__ h16, int M, int K)
{
    __shared__ short Bs[2][8192];            // 2 x 16 KB K-step tiles

    const int tid  = threadIdx.x;
    const int w    = tid >> 6;
    const int lane = tid & 63;
    const int quad = lane >> 4;
    const int ml   = lane & 15;
    const int bm   = blockIdx.x * 64;

    const int rowA = bm + w * 16 + ml;
    const int rowL = rowA < M ? rowA : M - 1;

    f32x4 acc[16];
    #pragma unroll
    for (int nb = 0; nb < 16; ++nb) acc[nb] = (f32x4){0.f, 0.f, 0.f, 0.f};

    const float* A32 = (const float*)Aptr;
    const short* A16 = (const short*)Aptr;
    const int nsteps = K >> 5;

    // ---- stage B step 0 into buffer 0 (4 x 1KB per wave) ----
    {
        const short* g = Bf + (size_t)w * 2048 + lane * 8;
        short* l = &Bs[0][w * 2048];
        #pragma unroll
        for (int c = 0; c < 4; ++c) gl2lds16(g + c * 512, l + c * 512);
    }

    // ---- A prefetch for step 0 ----
    float4 p0, p1;
    bf16x8 pb;
    if (ABF16) {
        pb = *(const bf16x8*)(A16 + (size_t)rowL * K + quad * 8);
    } else {
        const float* ap = A32 + (size_t)rowL * K + quad * 8;
        p0 = *(const float4*)(ap);
        p1 = *(const float4*)(ap + 4);
    }

    for (int s = 0; s < nsteps; ++s) {
        __syncthreads();   // staging of buf (s&1) + A prefetch complete

        // async-stage next step's B into the other buffer
        if (s + 1 < nsteps) {
            const short* g = Bf + (size_t)(s + 1) * 8192 + w * 2048 + lane * 8;
            short* l = &Bs[(s + 1) & 1][w * 2048];
            #pragma unroll
            for (int c = 0; c < 4; ++c) gl2lds16(g + c * 512, l + c * 512);
        }

        // A fragment for this step; prefetch next
        bf16x8 af;
        if (ABF16) {
            af = pb;
            if (s + 1 < nsteps)
                pb = *(const bf16x8*)(A16 + (size_t)rowL * K + (s + 1) * 32 + quad * 8);
        } else {
            af[0] = f2bf(p0.x); af[1] = f2bf(p0.y); af[2] = f2bf(p0.z); af[3] = f2bf(p0.w);
            af[4] = f2bf(p1.x); af[5] = f2bf(p1.y); af[6] = f2bf(p1.z); af[7] = f2bf(p1.w);
            if (s + 1 < nsteps) {
                const float* ap = A32 + (size_t)rowL * K + (s + 1) * 32 + quad * 8;
                p0 = *(const float4*)(ap);
                p1 = *(const float4*)(ap + 4);
            }
        }

        const short* bsrc = &Bs[s & 1][lane * 8];
        #pragma unroll
        for (int nb = 0; nb < 16; ++nb) {
            bf16x8 bfr = *(const bf16x8*)(bsrc + nb * 512);   // ds_read_b128
            acc[nb] = __builtin_amdgcn_mfma_f32_16x16x32_bf16(af, bfr, acc[nb], 0, 0, 0);
        }
    }

    #pragma unroll
    for (int r = 0; r < 4; ++r) {
        int row = bm + w * 16 + quad * 4 + r;
        if (row < M) {
            #pragma unroll
            for (int nb = 0; nb < 16; ++nb)
                h16[(size_t)row * HC + nb * 16 + ml] = (_Float16)acc[nb][r];
        }
    }
}

// ---------------------------------------------------------------------------
// alpha_s[n,h] = sum_c h[n,h,c]*a_s[h,c]; same for a_d.
// ---------------------------------------------------------------------------
__global__ __launch_bounds__(256) void alphas_kernel(const _Float16* __restrict__ h16,
    const float* __restrict__ a_s, const float* __restrict__ a_d,
    float* __restrict__ alpha_s, float* __restrict__ alpha_d)
{
    const int n = blockIdx.x;
    const int t = threadIdx.x;
    float v = (float)h16[(size_t)n * HC + t];
    float ps = v * a_s[t];
    float pd = v * a_d[t];
    #pragma unroll
    for (int off = 16; off > 0; off >>= 1) {
        ps += __shfl_xor(ps, off);
        pd += __shfl_xor(pd, off);
    }
    if ((t & 31) == 0) {
        int hh = t >> 5;
        alpha_s[(size_t)n * H_HEADS + hh] = ps;
        alpha_d[(size_t)n * H_HEADS + hh] = pd;
    }
}

// ---------------------------------------------------------------------------
// Per-edge softmax weights: w[p,h] = exp(leaky(alpha_s[src]+alpha_d[dst])).
// ---------------------------------------------------------------------------
__global__ __launch_bounds__(256) void wcalc_kernel(const int* __restrict__ src_sorted,
    const int* __restrict__ dst_sorted, const float* __restrict__ alpha_s,
    const float* __restrict__ alpha_d, float* __restrict__ wq, int P)
{
    int p = blockIdx.x * 256 + threadIdx.x;
    if (p >= P) return;
    int s = src_sorted[p], d = dst_sorted[p];
    const float4* as = (const float4*)(alpha_s + (size_t)s * H_HEADS);
    const float4* ad = (const float4*)(alpha_d + (size_t)d * H_HEADS);
    float4 s0 = as[0], s1 = as[1], d0 = ad[0], d1 = ad[1];
    float e[8] = {s0.x + d0.x, s0.y + d0.y, s0.z + d0.z, s0.w + d0.w,
                  s1.x + d1.x, s1.y + d1.y, s1.z + d1.z, s1.w + d1.w};
    float4 o0, o1;
    #pragma unroll
    for (int h = 0; h < 8; ++h) {
        float v = e[h] > 0.f ? e[h] : NEG_SLOPE * e[h];
        (h < 4 ? ((float*)&o0)[h] : ((float*)&o1)[h - 4]) = __expf(v);
    }
    float4* op = (float4*)(wq + (size_t)p * H_HEADS);
    op[0] = o0; op[1] = o1;
}

// ---------------------------------------------------------------------------
// CSR build
// ---------------------------------------------------------------------------
__global__ void zero_int(int* __restrict__ p, int n)
{
    int i = blockIdx.x * 256 + threadIdx.x;
    if (i < n) p[i] = 0;
}

__global__ void hist_kernel(const int* __restrict__ ei, int E, int N,
                            int* __restrict__ cnt)
{
    int e = blockIdx.x * 256 + threadIdx.x;
    if (e < E) atomicAdd(&cnt[ei[E + e]], 1);
    else if (e < E + N) atomicAdd(&cnt[e - E], 1);
}

__global__ __launch_bounds__(256) void scan_sum(const int* __restrict__ cnt, int n,
                                                int* __restrict__ chunk_sum)
{
    __shared__ int lds[256];
    int b = blockIdx.x, t = threadIdx.x;
    int base = b * 1024 + t * 4;
    int s = 0;
    #pragma unroll
    for (int j = 0; j < 4; ++j) { int i = base + j; if (i < n) s += cnt[i]; }
    lds[t] = s; __syncthreads();
    for (int off = 128; off > 0; off >>= 1) {
        if (t < off) lds[t] += lds[t + off];
        __syncthreads();
    }
    if (t == 0) chunk_sum[b] = lds[0];
}

__global__ void scan_top(const int* __restrict__ chunk_sum, int nch,
                         int* __restrict__ chunk_off, int* __restrict__ row_ptr,
                         int n_nodes)
{
    int t = threadIdx.x;
    int v = (t < nch) ? chunk_sum[t] : 0;
    int inc = v;
    #pragma unroll
    for (int off = 1; off < 64; off <<= 1) {
        int u = __shfl_up(inc, off);
        if (t >= off) inc += u;
    }
    if (t < nch) chunk_off[t] = inc - v;
    if (t == 63) row_ptr[n_nodes] = inc;
}

__global__ __launch_bounds__(256) void scan_local(const int* __restrict__ cnt, int n,
    const int* __restrict__ chunk_off, int* __restrict__ row_ptr)
{
    __shared__ int lds[256];
    int b = blockIdx.x, t = threadIdx.x;
    int base = b * 1024 + t * 4;
    int v[4]; int s = 0;
    #pragma unroll
    for (int j = 0; j < 4; ++j) { int i = base + j; v[j] = (i < n) ? cnt[i] : 0; s += v[j]; }
    lds[t] = s; __syncthreads();
    for (int off = 1; off < 256; off <<= 1) {
        int u = (t >= off) ? lds[t - off] : 0;
        __syncthreads();
        lds[t] += u;
        __syncthreads();
    }
    int run = lds[t] - s + chunk_off[b];
    #pragma unroll
    for (int j = 0; j < 4; ++j) {
        int i = base + j;
        if (i < n) row_ptr[i] = run;
        run += v[j];
    }
}

__global__ void scatter_kernel(const int* __restrict__ ei, int E, int N,
    const int* __restrict__ row_ptr, int* __restrict__ fill,
    int* __restrict__ src_sorted, int* __restrict__ dst_sorted)
{
    int e = blockIdx.x * 256 + threadIdx.x;
    int src, dst;
    if (e < E)          { src = ei[e]; dst = ei[E + e]; }
    else if (e < E + N) { src = dst = e - E; }
    else return;
    int pos = row_ptr[dst] + atomicAdd(&fill[dst], 1);
    src_sorted[pos] = src;
    dst_sorted[pos] = dst;
}

// ---------------------------------------------------------------------------
// Layer-1 aggregation: one wave per dst node, lane owns 4 channels, x4 unroll.
// ---------------------------------------------------------------------------
__global__ __launch_bounds__(256) void agg1_kernel(const _Float16* __restrict__ h16,
    const float* __restrict__ wq, const int* __restrict__ row_ptr,
    const int* __restrict__ src_sorted, const float* __restrict__ bias,
    short* __restrict__ z_bf, int N)
{
    const int l = threadIdx.x & 63;
    const int i = blockIdx.x * 4 + (threadIdx.x >> 6);
    if (i >= N) return;
    const int hh = l >> 3;
    const int beg = row_ptr[i], end = row_ptr[i + 1];
    f32x4 acc = {0.f, 0.f, 0.f, 0.f};
    float dsum = 0.f;
    int p = beg;
    for (; p + 3 < end; p += 4) {
        int s0 = src_sorted[p], s1 = src_sorted[p + 1];
        int s2 = src_sorted[p + 2], s3 = src_sorted[p + 3];
        float w0 = wq[(size_t)p * 8 + hh];
        float w1 = wq[(size_t)(p + 1) * 8 + hh];
        float w2 = wq[(size_t)(p + 2) * 8 + hh];
        float w3 = wq[(size_t)(p + 3) * 8 + hh];
        h16x4 v0 = *(const h16x4*)(h16 + (size_t)s0 * HC + 4 * l);
        h16x4 v1 = *(const h16x4*)(h16 + (size_t)s1 * HC + 4 * l);
        h16x4 v2 = *(const h16x4*)(h16 + (size_t)s2 * HC + 4 * l);
        h16x4 v3 = *(const h16x4*)(h16 + (size_t)s3 * HC + 4 * l);
        #pragma unroll
        for (int j = 0; j < 4; ++j) {
            acc[j] = fmaf(w0, (float)v0[j], acc[j]);
            acc[j] = fmaf(w1, (float)v1[j], acc[j]);
            acc[j] = fmaf(w2, (float)v2[j], acc[j]);
            acc[j] = fmaf(w3, (float)v3[j], acc[j]);
        }
        dsum += (w0 + w1) + (w2 + w3);
    }
    for (; p < end; ++p) {
        int s0 = src_sorted[p];
        float w0 = wq[(size_t)p * 8 + hh];
        h16x4 v0 = *(const h16x4*)(h16 + (size_t)s0 * HC + 4 * l);
        #pragma unroll
        for (int j = 0; j < 4; ++j) acc[j] = fmaf(w0, (float)v0[j], acc[j]);
        dsum += w0;
    }
    float inv = 1.f / (dsum + 1e-16f);
    s16x4 pk;
    #pragma unroll
    for (int j = 0; j < 4; ++j) {
        float z = acc[j] * inv + bias[4 * l + j];
        pk[j] = f2bf(z > 0.f ? z : 0.f);
    }
    *(s16x4*)(z_bf + (size_t)i * HC + 4 * l) = pk;
}

// ---------------------------------------------------------------------------
// Layer-2 aggregation fused with head-mean + b2 + Wp dot + sigmoid.
// ---------------------------------------------------------------------------
__global__ __launch_bounds__(256) void agg2_kernel(const _Float16* __restrict__ h16,
    const float* __restrict__ wq, const int* __restrict__ row_ptr,
    const int* __restrict__ src_sorted, const float* __restrict__ b2,
    const float* __restrict__ Wp, const float* __restrict__ bp,
    float* __restrict__ out, int N)
{
    const int l = threadIdx.x & 63;
    const int i = blockIdx.x * 4 + (threadIdx.x >> 6);
    if (i >= N) return;
    const int hh = l >> 3;
    const int beg = row_ptr[i], end = row_ptr[i + 1];
    f32x4 acc = {0.f, 0.f, 0.f, 0.f};
    float dsum = 0.f;
    int p = beg;
    for (; p + 3 < end; p += 4) {
        int s0 = src_sorted[p], s1 = src_sorted[p + 1];
        int s2 = src_sorted[p + 2], s3 = src_sorted[p + 3];
        float w0 = wq[(size_t)p * 8 + hh];
        float w1 = wq[(size_t)(p + 1) * 8 + hh];
        float w2 = wq[(size_t)(p + 2) * 8 + hh];
        float w3 = wq[(size_t)(p + 3) * 8 + hh];
        h16x4 v0 = *(const h16x4*)(h16 + (size_t)s0 * HC + 4 * l);
        h16x4 v1 = *(const h16x4*)(h16 + (size_t)s1 * HC + 4 * l);
        h16x4 v2 = *(const h16x4*)(h16 + (size_t)s2 * HC + 4 * l);
        h16x4 v3 = *(const h16x4*)(h16 + (size_t)s3 * HC + 4 * l);
        #pragma unroll
        for (int j = 0; j < 4; ++j) {
            acc[j] = fmaf(w0, (float)v0[j], acc[j]);
            acc[j] = fmaf(w1, (float)v1[j], acc[j]);
            acc[j] = fmaf(w2, (float)v2[j], acc[j]);
            acc[j] = fmaf(w3, (float)v3[j], acc[j]);
        }
        dsum += (w0 + w1) + (w2 + w3);
    }
    for (; p < end; ++p) {
        int s0 = src_sorted[p];
        float w0 = wq[(size_t)p * 8 + hh];
        h16x4 v0 = *(const h16x4*)(h16 + (size_t)s0 * HC + 4 * l);
        #pragma unroll
        for (int j = 0; j < 4; ++j) acc[j] = fmaf(w0, (float)v0[j], acc[j]);
        dsum += w0;
    }
    float inv = 1.f / (dsum + 1e-16f);
    int cc = (4 * l) & 31;
    float partial = 0.f;
    #pragma unroll
    for (int j = 0; j < 4; ++j) partial = fmaf(acc[j] * inv, Wp[cc + j], partial);
    if (l < 8) {
        #pragma unroll
        for (int j = 0; j < 4; ++j) partial = fmaf(8.f * b2[4 * l + j], Wp[4 * l + j], partial);
    }
    #pragma unroll
    for (int off = 32; off > 0; off >>= 1) partial += __shfl_xor(partial, off);
    if (l == 0) out[i] = 1.f / (1.f + __expf(-(0.125f * partial + bp[0])));
}

// ---------------------------------------------------------------------------
extern "C" void kernel_launch(void* const* d_in, const int* in_sizes, int n_in,
                              void* d_out, int out_size, void* d_ws, size_t ws_size,
                              hipStream_t stream)
{
    const int*   ei  = (const int*)d_in[0];
    const float* x   = (const float*)d_in[1];
    const float* W1  = (const float*)d_in[2];
    const float* as1 = (const float*)d_in[3];
    const float* ad1 = (const float*)d_in[4];
    const float* b1  = (const float*)d_in[5];
    const float* W2  = (const float*)d_in[6];
    const float* as2 = (const float*)d_in[7];
    const float* ad2 = (const float*)d_in[8];
    const float* b2  = (const float*)d_in[9];
    const float* Wp  = (const float*)d_in[10];
    const float* bp  = (const float*)d_in[11];
    float* out = (float*)d_out;

    const int E = in_sizes[0] / 2;
    const int N = in_sizes[1] / F_IN;
    const int ET = E + N;

    // workspace layout
    float*    asb = (float*)d_ws;                          // N*8
    float*    adb = asb + (size_t)N * H_HEADS;             // N*8
    _Float16* h16 = (_Float16*)(adb + (size_t)N * H_HEADS);// N*256
    short*    z1b = (short*)(h16 + (size_t)N * HC);        // N*256 bf16
    short*    Wf1 = z1b + (size_t)N * HC;                  // 512*256
    short*    Wf2 = Wf1 + (size_t)F_IN * HC;               // 256*256
    float*    wq  = (float*)(Wf2 + (size_t)HC * HC);       // (E+N)*8
    int* cnt       = (int*)(wq + (size_t)ET * H_HEADS);    // N
    int* fill      = cnt + N;                              // N
    int* row_ptr   = fill + N;                             // N+1
    int* chunk_off = row_ptr + N + 1;                      // 64
    int* chunk_sum = chunk_off + 64;                       // 64
    int* src_sorted = chunk_sum + 64;                      // E+N
    int* dst_sorted = src_sorted + ET;                     // E+N

    const int NCH = (N + 1023) / 1024;
    const int MB  = (N + 63) / 64;
    const int NB4 = (N + 3) / 4;

    // ---- CSR build ----
    zero_int<<<(2 * N + 255) / 256, 256, 0, stream>>>(cnt, 2 * N);
    hist_kernel<<<(ET + 255) / 256, 256, 0, stream>>>(ei, E, N, cnt);
    scan_sum<<<NCH, 256, 0, stream>>>(cnt, N, chunk_sum);
    scan_top<<<1, 64, 0, stream>>>(chunk_sum, NCH, chunk_off, row_ptr, N);
    scan_local<<<NCH, 256, 0, stream>>>(cnt, N, chunk_off, row_ptr);
    scatter_kernel<<<(ET + 255) / 256, 256, 0, stream>>>(ei, E, N, row_ptr, fill,
                                                         src_sorted, dst_sorted);

    // ---- W repack ----
    wfrag_kernel<<<(F_IN * HC + 255) / 256, 256, 0, stream>>>(W1, Wf1, F_IN);
    wfrag_kernel<<<(HC * HC + 255) / 256, 256, 0, stream>>>(W2, Wf2, HC);

    // ---- Layer 1 ----
    gemm_mfma<false><<<MB, 256, 0, stream>>>(x, Wf1, h16, N, F_IN);
    alphas_kernel<<<N, 256, 0, stream>>>(h16, as1, ad1, asb, adb);
    wcalc_kernel<<<(ET + 255) / 256, 256, 0, stream>>>(src_sorted, dst_sorted, asb, adb, wq, ET);
    agg1_kernel<<<NB4, 256, 0, stream>>>(h16, wq, row_ptr, src_sorted, b1, z1b, N);

    // ---- Layer 2 ----
    gemm_mfma<true><<<MB, 256, 0, stream>>>(z1b, Wf2, h16, N, HC);
    alphas_kernel<<<N, 256, 0, stream>>>(h16, as2, ad2, asb, adb);
    wcalc_kernel<<<(ET + 255) / 256, 256, 0, stream>>>(src_sorted, dst_sorted, asb, adb, wq, ET);
    agg2_kernel<<<NB4, 256, 0, stream>>>(h16, wq, row_ptr, src_sorted, b2, Wp, bp, out, N);
}

// Round 5
// 423.175 us; speedup vs baseline: 2.2148x; 1.1901x over previous
//
#include <hip/hip_runtime.h>
#include <math.h>

#define H_HEADS 8
#define C_DIM   32
#define HC      256
#define F_IN    512
#define NEG_SLOPE 0.2f

typedef __attribute__((ext_vector_type(8))) short    bf16x8;
typedef __attribute__((ext_vector_type(4))) short    s16x4;
typedef __attribute__((ext_vector_type(4))) float    f32x4;
typedef __attribute__((ext_vector_type(2))) float    f32x2;
typedef __attribute__((ext_vector_type(8))) _Float16 h16x8;

__device__ __forceinline__ short f2bf(float f) {
    union { float f; unsigned u; } v; v.f = f;
    unsigned r = v.u + 0x7FFF + ((v.u >> 16) & 1);   // RNE
    return (short)(r >> 16);
}

__device__ __forceinline__ void gl2lds16(const short* g, short* l) {
    __builtin_amdgcn_global_load_lds(
        (const __attribute__((address_space(1))) void*)g,
        (__attribute__((address_space(3))) void*)l, 16, 0, 0);
}

// ---------------------------------------------------------------------------
// Repack W [K,256] fp32 -> MFMA B-frag-ordered bf16 (16 KB per K-step of 32).
// ---------------------------------------------------------------------------
__global__ void wfrag_kernel(const float* __restrict__ W, short* __restrict__ Wf, int K)
{
    int tid = blockIdx.x * 256 + threadIdx.x;
    if (tid >= K * HC) return;
    int j  = tid & 7;
    int l  = (tid >> 3) & 63;
    int nb = (tid >> 9) & 15;
    int s  = tid >> 13;
    int k  = s * 32 + (l >> 4) * 8 + j;
    int n  = nb * 16 + (l & 15);
    Wf[tid] = f2bf(W[(size_t)k * HC + n]);
}

// ---------------------------------------------------------------------------
// MFMA GEMM + fused epilogue:
//   h8[M,256] (fp8 e4m3, gather payload for agg)
//   alpha_s/alpha_d[M,8] = per-head dots with a_s/a_d (from fp32 accumulators)
// B staged global->LDS double-buffered; A register-prefetched (fp32 or bf16).
// ---------------------------------------------------------------------------
template<bool ABF16>
__global__ __launch_bounds__(256) void gemm_mfma(const void* __restrict__ Aptr,
    const short* __restrict__ Bf, unsigned char* __restrict__ h8,
    const float* __restrict__ a_s, const float* __restrict__ a_d,
    float* __restrict__ alpha_s, float* __restrict__ alpha_d, int M, int K)
{
    __shared__ short Bs[2][8192];            // 2 x 16 KB K-step tiles
    __shared__ float Als[512], Ald[512];     // 64 rows x 8 heads

    const int tid  = threadIdx.x;
    const int w    = tid >> 6;
    const int lane = tid & 63;
    const int quad = lane >> 4;
    const int ml   = lane & 15;
    const int bm   = blockIdx.x * 64;

    const int rowA = bm + w * 16 + ml;
    const int rowL = rowA < M ? rowA : M - 1;

    f32x4 acc[16];
    #pragma unroll
    for (int nb = 0; nb < 16; ++nb) acc[nb] = (f32x4){0.f, 0.f, 0.f, 0.f};

    const float* A32 = (const float*)Aptr;
    const short* A16 = (const short*)Aptr;
    const int nsteps = K >> 5;

    {   // stage B step 0
        const short* g = Bf + (size_t)w * 2048 + lane * 8;
        short* l = &Bs[0][w * 2048];
        #pragma unroll
        for (int c = 0; c < 4; ++c) gl2lds16(g + c * 512, l + c * 512);
    }

    float4 p0, p1;
    bf16x8 pb;
    if (ABF16) {
        pb = *(const bf16x8*)(A16 + (size_t)rowL * K + quad * 8);
    } else {
        const float* ap = A32 + (size_t)rowL * K + quad * 8;
        p0 = *(const float4*)(ap);
        p1 = *(const float4*)(ap + 4);
    }

    for (int s = 0; s < nsteps; ++s) {
        __syncthreads();

        if (s + 1 < nsteps) {
            const short* g = Bf + (size_t)(s + 1) * 8192 + w * 2048 + lane * 8;
            short* l = &Bs[(s + 1) & 1][w * 2048];
            #pragma unroll
            for (int c = 0; c < 4; ++c) gl2lds16(g + c * 512, l + c * 512);
        }

        bf16x8 af;
        if (ABF16) {
            af = pb;
            if (s + 1 < nsteps)
                pb = *(const bf16x8*)(A16 + (size_t)rowL * K + (s + 1) * 32 + quad * 8);
        } else {
            af[0] = f2bf(p0.x); af[1] = f2bf(p0.y); af[2] = f2bf(p0.z); af[3] = f2bf(p0.w);
            af[4] = f2bf(p1.x); af[5] = f2bf(p1.y); af[6] = f2bf(p1.z); af[7] = f2bf(p1.w);
            if (s + 1 < nsteps) {
                const float* ap = A32 + (size_t)rowL * K + (s + 1) * 32 + quad * 8;
                p0 = *(const float4*)(ap);
                p1 = *(const float4*)(ap + 4);
            }
        }

        const short* bsrc = &Bs[s & 1][lane * 8];
        #pragma unroll
        for (int nb = 0; nb < 16; ++nb) {
            bf16x8 bfr = *(const bf16x8*)(bsrc + nb * 512);
            acc[nb] = __builtin_amdgcn_mfma_f32_16x16x32_bf16(af, bfr, acc[nb], 0, 0, 0);
        }
    }

    // ---- epilogue: fp8 store + fused per-head alpha dots ----
    // lane owns channels c = nb*16+ml for rows bm + w*16 + quad*4 + r; head(c) = nb>>1
    float as_v[16], ad_v[16];
    #pragma unroll
    for (int nb = 0; nb < 16; ++nb) {
        as_v[nb] = a_s[nb * 16 + ml];
        ad_v[nb] = a_d[nb * 16 + ml];
    }

    #pragma unroll
    for (int r = 0; r < 4; ++r) {
        const int rl  = w * 16 + quad * 4 + r;
        const int row = bm + rl;

        if (row < M) {
            unsigned char* hrow = h8 + (size_t)row * HC;
            #pragma unroll
            for (int i = 0; i < 8; ++i) {
                int pk = __builtin_amdgcn_cvt_pk_fp8_f32(acc[2 * i][r], acc[2 * i + 1][r], 0, false);
                hrow[(2 * i) * 16 + ml]     = (unsigned char)(pk & 0xFF);
                hrow[(2 * i + 1) * 16 + ml] = (unsigned char)((pk >> 8) & 0xFF);
            }
        }

        float hs[8], hd[8];
        #pragma unroll
        for (int q = 0; q < 8; ++q) {
            hs[q] = acc[2 * q][r] * as_v[2 * q] + acc[2 * q + 1][r] * as_v[2 * q + 1];
            hd[q] = acc[2 * q][r] * ad_v[2 * q] + acc[2 * q + 1][r] * ad_v[2 * q + 1];
        }
        #pragma unroll
        for (int off = 1; off < 16; off <<= 1) {
            #pragma unroll
            for (int q = 0; q < 8; ++q) {
                hs[q] += __shfl_xor(hs[q], off);
                hd[q] += __shfl_xor(hd[q], off);
            }
        }
        if (ml == 0) {
            #pragma unroll
            for (int q = 0; q < 8; ++q) {
                Als[rl * 8 + q] = hs[q];
                Ald[rl * 8 + q] = hd[q];
            }
        }
    }
    __syncthreads();
    #pragma unroll
    for (int k = 0; k < 2; ++k) {
        int idx = tid + k * 256;
        int rl = idx >> 3, q = idx & 7;
        int row = bm + rl;
        if (row < M) {
            alpha_s[(size_t)row * H_HEADS + q] = Als[idx];
            alpha_d[(size_t)row * H_HEADS + q] = Ald[idx];
        }
    }
}

// ---------------------------------------------------------------------------
// Per-edge softmax weights (fp16): w[p,h] = exp(leaky(alpha_s[src]+alpha_d[dst]))
// ---------------------------------------------------------------------------
__global__ __launch_bounds__(256) void wcalc_kernel(const int2* __restrict__ es,
    const float* __restrict__ alpha_s, const float* __restrict__ alpha_d,
    _Float16* __restrict__ wq, int P)
{
    int p = blockIdx.x * 256 + threadIdx.x;
    if (p >= P) return;
    int2 sd = es[p];
    const float4* as = (const float4*)(alpha_s + (size_t)sd.x * H_HEADS);
    const float4* ad = (const float4*)(alpha_d + (size_t)sd.y * H_HEADS);
    float4 s0 = as[0], s1 = as[1], d0 = ad[0], d1 = ad[1];
    float e[8] = {s0.x + d0.x, s0.y + d0.y, s0.z + d0.z, s0.w + d0.w,
                  s1.x + d1.x, s1.y + d1.y, s1.z + d1.z, s1.w + d1.w};
    h16x8 o;
    #pragma unroll
    for (int h = 0; h < 8; ++h) {
        float v = e[h] > 0.f ? e[h] : NEG_SLOPE * e[h];
        o[h] = (_Float16)__expf(v);
    }
    *(h16x8*)(wq + (size_t)p * H_HEADS) = o;
}

// ---------------------------------------------------------------------------
// CSR build
// ---------------------------------------------------------------------------
__global__ void zero_int(int* __restrict__ p, int n)
{
    int i = blockIdx.x * 256 + threadIdx.x;
    if (i < n) p[i] = 0;
}

__global__ void hist_kernel(const int* __restrict__ ei, int E, int N,
                            int* __restrict__ cnt)
{
    int e = blockIdx.x * 256 + threadIdx.x;
    if (e < E) atomicAdd(&cnt[ei[E + e]], 1);
    else if (e < E + N) atomicAdd(&cnt[e - E], 1);
}

__global__ __launch_bounds__(256) void scan_sum(const int* __restrict__ cnt, int n,
                                                int* __restrict__ chunk_sum)
{
    __shared__ int lds[256];
    int b = blockIdx.x, t = threadIdx.x;
    int base = b * 1024 + t * 4;
    int s = 0;
    #pragma unroll
    for (int j = 0; j < 4; ++j) { int i = base + j; if (i < n) s += cnt[i]; }
    lds[t] = s; __syncthreads();
    for (int off = 128; off > 0; off >>= 1) {
        if (t < off) lds[t] += lds[t + off];
        __syncthreads();
    }
    if (t == 0) chunk_sum[b] = lds[0];
}

__global__ void scan_top(const int* __restrict__ chunk_sum, int nch,
                         int* __restrict__ chunk_off, int* __restrict__ row_ptr,
                         int n_nodes)
{
    int t = threadIdx.x;
    int v = (t < nch) ? chunk_sum[t] : 0;
    int inc = v;
    #pragma unroll
    for (int off = 1; off < 64; off <<= 1) {
        int u = __shfl_up(inc, off);
        if (t >= off) inc += u;
    }
    if (t < nch) chunk_off[t] = inc - v;
    if (t == 63) row_ptr[n_nodes] = inc;
}

__global__ __launch_bounds__(256) void scan_local(const int* __restrict__ cnt, int n,
    const int* __restrict__ chunk_off, int* __restrict__ row_ptr)
{
    __shared__ int lds[256];
    int b = blockIdx.x, t = threadIdx.x;
    int base = b * 1024 + t * 4;
    int v[4]; int s = 0;
    #pragma unroll
    for (int j = 0; j < 4; ++j) { int i = base + j; v[j] = (i < n) ? cnt[i] : 0; s += v[j]; }
    lds[t] = s; __syncthreads();
    for (int off = 1; off < 256; off <<= 1) {
        int u = (t >= off) ? lds[t - off] : 0;
        __syncthreads();
        lds[t] += u;
        __syncthreads();
    }
    int run = lds[t] - s + chunk_off[b];
    #pragma unroll
    for (int j = 0; j < 4; ++j) {
        int i = base + j;
        if (i < n) row_ptr[i] = run;
        run += v[j];
    }
}

__global__ void scatter_kernel(const int* __restrict__ ei, int E, int N,
    const int* __restrict__ row_ptr, int* __restrict__ fill, int2* __restrict__ es)
{
    int e = blockIdx.x * 256 + threadIdx.x;
    int src, dst;
    if (e < E)          { src = ei[e]; dst = ei[E + e]; }
    else if (e < E + N) { src = dst = e - E; }
    else return;
    int pos = row_ptr[dst] + atomicAdd(&fill[dst], 1);
    es[pos] = make_int2(src, dst);
}

// ---------------------------------------------------------------------------
// Layer-1 aggregation: one wave per dst node, lane owns 4 channels (fp8 dword
// gather), x8 unrolled edge loop. z written bf16 (layer-2 GEMM A input).
// ---------------------------------------------------------------------------
__global__ __launch_bounds__(256) void agg1_kernel(const unsigned* __restrict__ h8,
    const _Float16* __restrict__ wq, const int* __restrict__ row_ptr,
    const int2* __restrict__ es, const float* __restrict__ bias,
    short* __restrict__ z_bf, int N)
{
    const int l = threadIdx.x & 63;
    const int i = blockIdx.x * 4 + (threadIdx.x >> 6);
    if (i >= N) return;
    const int hh = l >> 3;
    const int beg = row_ptr[i], end = row_ptr[i + 1];
    f32x4 acc = {0.f, 0.f, 0.f, 0.f};
    float dsum = 0.f;
    int p = beg;
    for (; p + 7 < end; p += 8) {
        int s[8]; float w[8]; unsigned hv[8];
        #pragma unroll
        for (int u = 0; u < 8; ++u) s[u] = es[p + u].x;
        #pragma unroll
        for (int u = 0; u < 8; ++u) w[u] = (float)wq[(size_t)(p + u) * 8 + hh];
        #pragma unroll
        for (int u = 0; u < 8; ++u) hv[u] = h8[(size_t)s[u] * 64 + l];
        #pragma unroll
        for (int u = 0; u < 8; ++u) {
            f32x2 lo = __builtin_amdgcn_cvt_pk_f32_fp8(hv[u], false);
            f32x2 hi = __builtin_amdgcn_cvt_pk_f32_fp8(hv[u], true);
            acc[0] = fmaf(w[u], lo[0], acc[0]);
            acc[1] = fmaf(w[u], lo[1], acc[1]);
            acc[2] = fmaf(w[u], hi[0], acc[2]);
            acc[3] = fmaf(w[u], hi[1], acc[3]);
            dsum += w[u];
        }
    }
    for (; p < end; ++p) {
        int s0 = es[p].x;
        float w0 = (float)wq[(size_t)p * 8 + hh];
        unsigned hv = h8[(size_t)s0 * 64 + l];
        f32x2 lo = __builtin_amdgcn_cvt_pk_f32_fp8(hv, false);
        f32x2 hi = __builtin_amdgcn_cvt_pk_f32_fp8(hv, true);
        acc[0] = fmaf(w0, lo[0], acc[0]);
        acc[1] = fmaf(w0, lo[1], acc[1]);
        acc[2] = fmaf(w0, hi[0], acc[2]);
        acc[3] = fmaf(w0, hi[1], acc[3]);
        dsum += w0;
    }
    float inv = 1.f / (dsum + 1e-16f);
    s16x4 pk;
    #pragma unroll
    for (int j = 0; j < 4; ++j) {
        float z = acc[j] * inv + bias[4 * l + j];
        pk[j] = f2bf(z > 0.f ? z : 0.f);
    }
    *(s16x4*)(z_bf + (size_t)i * HC + 4 * l) = pk;
}

// ---------------------------------------------------------------------------
// Layer-2 aggregation fused with head-mean + b2 + Wp dot + sigmoid.
// ---------------------------------------------------------------------------
__global__ __launch_bounds__(256) void agg2_kernel(const unsigned* __restrict__ h8,
    const _Float16* __restrict__ wq, const int* __restrict__ row_ptr,
    const int2* __restrict__ es, const float* __restrict__ b2,
    const float* __restrict__ Wp, const float* __restrict__ bp,
    float* __restrict__ out, int N)
{
    const int l = threadIdx.x & 63;
    const int i = blockIdx.x * 4 + (threadIdx.x >> 6);
    if (i >= N) return;
    const int hh = l >> 3;
    const int beg = row_ptr[i], end = row_ptr[i + 1];
    f32x4 acc = {0.f, 0.f, 0.f, 0.f};
    float dsum = 0.f;
    int p = beg;
    for (; p + 7 < end; p += 8) {
        int s[8]; float w[8]; unsigned hv[8];
        #pragma unroll
        for (int u = 0; u < 8; ++u) s[u] = es[p + u].x;
        #pragma unroll
        for (int u = 0; u < 8; ++u) w[u] = (float)wq[(size_t)(p + u) * 8 + hh];
        #pragma unroll
        for (int u = 0; u < 8; ++u) hv[u] = h8[(size_t)s[u] * 64 + l];
        #pragma unroll
        for (int u = 0; u < 8; ++u) {
            f32x2 lo = __builtin_amdgcn_cvt_pk_f32_fp8(hv[u], false);
            f32x2 hi = __builtin_amdgcn_cvt_pk_f32_fp8(hv[u], true);
            acc[0] = fmaf(w[u], lo[0], acc[0]);
            acc[1] = fmaf(w[u], lo[1], acc[1]);
            acc[2] = fmaf(w[u], hi[0], acc[2]);
            acc[3] = fmaf(w[u], hi[1], acc[3]);
            dsum += w[u];
        }
    }
    for (; p < end; ++p) {
        int s0 = es[p].x;
        float w0 = (float)wq[(size_t)p * 8 + hh];
        unsigned hv = h8[(size_t)s0 * 64 + l];
        f32x2 lo = __builtin_amdgcn_cvt_pk_f32_fp8(hv, false);
        f32x2 hi = __builtin_amdgcn_cvt_pk_f32_fp8(hv, true);
        acc[0] = fmaf(w0, lo[0], acc[0]);
        acc[1] = fmaf(w0, lo[1], acc[1]);
        acc[2] = fmaf(w0, hi[0], acc[2]);
        acc[3] = fmaf(w0, hi[1], acc[3]);
        dsum += w0;
    }
    float inv = 1.f / (dsum + 1e-16f);
    int cc = (4 * l) & 31;
    float partial = 0.f;
    #pragma unroll
    for (int j = 0; j < 4; ++j) partial = fmaf(acc[j] * inv, Wp[cc + j], partial);
    if (l < 8) {
        #pragma unroll
        for (int j = 0; j < 4; ++j) partial = fmaf(8.f * b2[4 * l + j], Wp[4 * l + j], partial);
    }
    #pragma unroll
    for (int off = 32; off > 0; off >>= 1) partial += __shfl_xor(partial, off);
    if (l == 0) out[i] = 1.f / (1.f + __expf(-(0.125f * partial + bp[0])));
}

// ---------------------------------------------------------------------------
extern "C" void kernel_launch(void* const* d_in, const int* in_sizes, int n_in,
                              void* d_out, int out_size, void* d_ws, size_t ws_size,
                              hipStream_t stream)
{
    const int*   ei  = (const int*)d_in[0];
    const float* x   = (const float*)d_in[1];
    const float* W1  = (const float*)d_in[2];
    const float* as1 = (const float*)d_in[3];
    const float* ad1 = (const float*)d_in[4];
    const float* b1  = (const float*)d_in[5];
    const float* W2  = (const float*)d_in[6];
    const float* as2 = (const float*)d_in[7];
    const float* ad2 = (const float*)d_in[8];
    const float* b2  = (const float*)d_in[9];
    const float* Wp  = (const float*)d_in[10];
    const float* bp  = (const float*)d_in[11];
    float* out = (float*)d_out;

    const int E = in_sizes[0] / 2;
    const int N = in_sizes[1] / F_IN;
    const int ET = E + N;

    // workspace layout (16B-aligned sections)
    float*         asb = (float*)d_ws;                           // N*8 f32
    float*         adb = asb + (size_t)N * H_HEADS;              // N*8 f32
    unsigned char* h8  = (unsigned char*)(adb + (size_t)N * H_HEADS); // N*256 fp8
    short*         z1b = (short*)(h8 + (size_t)N * HC);          // N*256 bf16
    short*         Wf1 = z1b + (size_t)N * HC;                   // 512*256 bf16
    short*         Wf2 = Wf1 + (size_t)F_IN * HC;                // 256*256 bf16
    _Float16*      wq  = (_Float16*)(Wf2 + (size_t)HC * HC);     // (E+N)*8 fp16
    int2*          es  = (int2*)(wq + (size_t)ET * H_HEADS);     // (E+N) int2
    int* cnt       = (int*)(es + ET);                            // N
    int* fill      = cnt + N;                                    // N
    int* row_ptr   = fill + N;                                   // N+1
    int* chunk_off = row_ptr + N + 1;                            // 64
    int* chunk_sum = chunk_off + 64;                             // 64

    const int NCH = (N + 1023) / 1024;
    const int MB  = (N + 63) / 64;
    const int NB4 = (N + 3) / 4;

    // ---- CSR build ----
    zero_int<<<(2 * N + 255) / 256, 256, 0, stream>>>(cnt, 2 * N);
    hist_kernel<<<(ET + 255) / 256, 256, 0, stream>>>(ei, E, N, cnt);
    scan_sum<<<NCH, 256, 0, stream>>>(cnt, N, chunk_sum);
    scan_top<<<1, 64, 0, stream>>>(chunk_sum, NCH, chunk_off, row_ptr, N);
    scan_local<<<NCH, 256, 0, stream>>>(cnt, N, chunk_off, row_ptr);
    scatter_kernel<<<(ET + 255) / 256, 256, 0, stream>>>(ei, E, N, row_ptr, fill, es);

    // ---- W repack ----
    wfrag_kernel<<<(F_IN * HC + 255) / 256, 256, 0, stream>>>(W1, Wf1, F_IN);
    wfrag_kernel<<<(HC * HC + 255) / 256, 256, 0, stream>>>(W2, Wf2, HC);

    // ---- Layer 1 ----
    gemm_mfma<false><<<MB, 256, 0, stream>>>(x, Wf1, h8, as1, ad1, asb, adb, N, F_IN);
    wcalc_kernel<<<(ET + 255) / 256, 256, 0, stream>>>(es, asb, adb, wq, ET);
    agg1_kernel<<<NB4, 256, 0, stream>>>((const unsigned*)h8, wq, row_ptr, es, b1, z1b, N);

    // ---- Layer 2 ----
    gemm_mfma<true><<<MB, 256, 0, stream>>>(z1b, Wf2, h8, as2, ad2, asb, adb, N, HC);
    wcalc_kernel<<<(ET + 255) / 256, 256, 0, stream>>>(es, asb, adb, wq, ET);
    agg2_kernel<<<NB4, 256, 0, stream>>>((const unsigned*)h8, wq, row_ptr, es, b2, Wp, bp, out, N);
}